// Round 3
// baseline (764.611 us; speedup 1.0000x reference)
//
#include <hip/hip_runtime.h>
#include <hip/hip_bf16.h>

#define B_     2
#define N_     32768
#define DIM_   256
#define H_     8
#define DH_    32
#define S_     64
#define INNER_ 256
#define BN_    (B_*N_)

#define WSTRIDE 20   // W-tile LDS row stride (floats): (20*iq)%32 spreads all 32 banks

typedef unsigned short ushort_t;
typedef unsigned int   uint_t;

static __device__ __forceinline__ float bf2f(ushort_t u){
  union { uint_t i; float f; } c; c.i = ((uint_t)u) << 16; return c.f;
}
static __device__ __forceinline__ ushort_t f2bf(float f){
  union { float f; uint_t i; } c; c.f = f;
  uint_t x = c.i;
  uint_t r = x + 0x7fffu + ((x >> 16) & 1u);   // RNE
  return (ushort_t)(r >> 16);
}
static __device__ __forceinline__ float dot4(float4 a, float4 b, float acc){
  acc = fmaf(a.x, b.x, acc); acc = fmaf(a.y, b.y, acc);
  acc = fmaf(a.z, b.z, acc); acc = fmaf(a.w, b.w, acc);
  return acc;
}

// ---------------------------------------------------------------------------
// K1: per-token projections (x@Wx.T, x@Wf.T), slice_proj, temp-softmax.
// grid = BN/32, block = 256.  LDS: x[32][256] (32KB) + Wx/Wf tiles [256][20]
// (20KB each, stride-20 = bank-conflict-free) = 72KB -> 2 blocks/CU.
// launch_bounds(256,2): 4 would cap VGPRs at 128 and spill sp[64]+xmr[32].
// ---------------------------------------------------------------------------
__global__ __launch_bounds__(256, 2)
void k1_proj(const float* __restrict__ x,
             const float* __restrict__ Wx, const float* __restrict__ bx,
             const float* __restrict__ Wf, const float* __restrict__ bf,
             const float* __restrict__ Ws, const float* __restrict__ bs,
             const float* __restrict__ temp,
             ushort_t* __restrict__ fm_bf, ushort_t* __restrict__ w_bf)
{
  __shared__ float smem[8192 + 2*256*WSTRIDE];   // 72KB
  float* x_l  = smem;                    // [32][256]
  float* wx_t = smem + 8192;             // [256][WSTRIDE]
  float* wf_t = smem + 8192 + 256*WSTRIDE;
  float* xm_l = smem;                    // [32][260], aliases x_l (+wx_t head)

  const int tid = threadIdx.x;
  const int n0  = blockIdx.x * 32;

  // stage x tile (coalesced float4)
  #pragma unroll
  for (int j = 0; j < 8; ++j){
    int idx = j*256 + tid;               // float4 index
    int tok = idx >> 6, kq = (idx & 63) << 2;
    *(float4*)&x_l[tok*256 + kq] = *(const float4*)&x[(size_t)(n0+tok)*256 + kq];
  }

  const int ttg = tid >> 6;              // wave id: 4 token groups of 8
  const int iq  = tid & 63;              // lane: output i = iq + 64*m
  float accx[8][4], accf[8][4];
  #pragma unroll
  for (int tt = 0; tt < 8; ++tt)
    #pragma unroll
    for (int m = 0; m < 4; ++m){ accx[tt][m] = 0.f; accf[tt][m] = 0.f; }

  for (int c = 0; c < 16; ++c){          // K chunks of 16
    __syncthreads();
    #pragma unroll
    for (int j = 0; j < 4; ++j){         // stage W chunk
      int idx = j*256 + tid;             // float4 index (1024 per matrix)
      int row = idx >> 2, kk = (idx & 3) << 2;
      *(float4*)&wx_t[row*WSTRIDE + kk] = *(const float4*)&Wx[row*256 + c*16 + kk];
      *(float4*)&wf_t[row*WSTRIDE + kk] = *(const float4*)&Wf[row*256 + c*16 + kk];
    }
    __syncthreads();
    #pragma unroll
    for (int k4 = 0; k4 < 4; ++k4){
      const int kb = c*16 + k4*4;
      float4 xa[8];
      #pragma unroll
      for (int tt = 0; tt < 8; ++tt)
        xa[tt] = *(const float4*)&x_l[(ttg*8+tt)*256 + kb];   // wave-uniform: broadcast
      #pragma unroll
      for (int m = 0; m < 4; ++m){
        const float4 wa = *(const float4*)&wx_t[(iq + 64*m)*WSTRIDE + k4*4];
        const float4 wb = *(const float4*)&wf_t[(iq + 64*m)*WSTRIDE + k4*4];
        #pragma unroll
        for (int tt = 0; tt < 8; ++tt){
          accx[tt][m] = dot4(xa[tt], wa, accx[tt][m]);
          accf[tt][m] = dot4(xa[tt], wb, accf[tt][m]);
        }
      }
    }
  }
  __syncthreads();

  // write xm (+bias) to LDS, fm (+bias) to global bf16
  float bxr[4], bfr[4];
  #pragma unroll
  for (int m = 0; m < 4; ++m){ bxr[m] = bx[iq + 64*m]; bfr[m] = bf[iq + 64*m]; }
  #pragma unroll
  for (int tt = 0; tt < 8; ++tt){
    const int t = ttg*8 + tt;
    const size_t n = (size_t)(n0 + t);
    #pragma unroll
    for (int m = 0; m < 4; ++m){
      xm_l[t*260 + iq + 64*m] = accx[tt][m] + bxr[m];
      fm_bf[n*256 + iq + 64*m] = f2bf(accf[tt][m] + bfr[m]);
    }
  }
  __syncthreads();

  // phase 2: slice_proj + softmax; thread = (token t2, head h)
  const int t2 = tid >> 3, h = tid & 7;
  const size_t n = (size_t)(n0 + t2);
  float xmr[32];
  #pragma unroll
  for (int d4 = 0; d4 < 8; ++d4)
    *(float4*)&xmr[d4*4] = *(const float4*)&xm_l[t2*260 + h*32 + d4*4];

  float tmpr = temp[h];
  tmpr = fminf(fmaxf(tmpr, 0.5f), 5.0f);

  float sp[64];
  #pragma unroll
  for (int s = 0; s < 64; ++s){
    float acc = bs[s];
    #pragma unroll
    for (int d4 = 0; d4 < 8; ++d4){
      float4 wv = *(const float4*)&Ws[s*32 + d4*4];   // wave-uniform: scalar loads
      acc = fmaf(xmr[d4*4+0], wv.x, acc);
      acc = fmaf(xmr[d4*4+1], wv.y, acc);
      acc = fmaf(xmr[d4*4+2], wv.z, acc);
      acc = fmaf(xmr[d4*4+3], wv.w, acc);
    }
    sp[s] = acc / tmpr;
  }
  float mx = sp[0];
  #pragma unroll
  for (int s = 1; s < 64; ++s) mx = fmaxf(mx, sp[s]);
  float sum = 0.f;
  #pragma unroll
  for (int s = 0; s < 64; ++s){ sp[s] = __expf(sp[s] - mx); sum += sp[s]; }
  const float inv = 1.0f / sum;

  uint4* dst = (uint4*)&w_bf[n*512 + h*64];
  #pragma unroll
  for (int j = 0; j < 8; ++j){
    uint4 pk;
    pk.x = (uint_t)f2bf(sp[8*j+0]*inv) | ((uint_t)f2bf(sp[8*j+1]*inv) << 16);
    pk.y = (uint_t)f2bf(sp[8*j+2]*inv) | ((uint_t)f2bf(sp[8*j+3]*inv) << 16);
    pk.z = (uint_t)f2bf(sp[8*j+4]*inv) | ((uint_t)f2bf(sp[8*j+5]*inv) << 16);
    pk.w = (uint_t)f2bf(sp[8*j+6]*inv) | ((uint_t)f2bf(sp[8*j+7]*inv) << 16);
    dst[j] = pk;
  }
}

// ---------------------------------------------------------------------------
// K2: slice_token_raw[b,h,s,d] = sum_n w*fm ; slice_norm[b,h,s] = sum_n w
// grid = (64 chunks, H, B), block = 256. Division by norm postponed to K3.
// ---------------------------------------------------------------------------
__global__ __launch_bounds__(256)
void k2_slicetok(const ushort_t* __restrict__ w_bf,
                 const ushort_t* __restrict__ fm_bf,
                 float* __restrict__ st_raw, float* __restrict__ norm)
{
  __shared__ float wg[8][64];
  __shared__ float fg[8][32];
  __shared__ float nred[8][64];

  const int tid = threadIdx.x;
  const int b = blockIdx.z, h = blockIdx.y, chunk = blockIdx.x;
  const int n0 = b*N_ + chunk*512;
  const int s = tid >> 2, dq = tid & 3;
  const int lg = tid >> 5, ls2 = tid & 31;

  float acc[8];
  #pragma unroll
  for (int k = 0; k < 8; ++k) acc[k] = 0.f;
  float nacc0 = 0.f, nacc1 = 0.f;

  for (int it = 0; it < 64; ++it){
    const int nb = n0 + it*8;
    __syncthreads();
    {
      uint_t wu = *(const uint_t*)&w_bf[(size_t)(nb+lg)*512 + h*64 + ls2*2];
      float w0 = bf2f((ushort_t)(wu & 0xffff));
      float w1 = bf2f((ushort_t)(wu >> 16));
      wg[lg][ls2*2]   = w0;
      wg[lg][ls2*2+1] = w1;
      nacc0 += w0; nacc1 += w1;
      fg[lg][ls2] = bf2f(fm_bf[(size_t)(nb+lg)*256 + h*32 + ls2]);
    }
    __syncthreads();
    #pragma unroll
    for (int g = 0; g < 8; ++g){
      const float wv = wg[g][s];
      #pragma unroll
      for (int k = 0; k < 8; ++k)
        acc[k] = fmaf(wv, fg[g][dq*8 + k], acc[k]);
    }
  }
  #pragma unroll
  for (int k = 0; k < 8; ++k)
    atomicAdd(&st_raw[((size_t)(b*8 + h)*64 + s)*32 + dq*8 + k], acc[k]);

  __syncthreads();
  nred[lg][2*ls2]   = nacc0;
  nred[lg][2*ls2+1] = nacc1;
  __syncthreads();
  if (tid < 64){
    float t = 0.f;
    #pragma unroll
    for (int g = 0; g < 8; ++g) t += nred[g][tid];
    atomicAdd(&norm[(b*8 + h)*64 + tid], t);
  }
}

// ---------------------------------------------------------------------------
// K3: tiny SDPA over slices per (b,h). grid = 16, block = 256.
// ---------------------------------------------------------------------------
__global__ __launch_bounds__(256)
void k3_attn(const float* __restrict__ st_raw, const float* __restrict__ norm,
             const float* __restrict__ Wqkv, float* __restrict__ out_sl)
{
  __shared__ float st_l[64][36];
  __shared__ float wq_l[96][36];
  __shared__ float qkv_l[64][100];
  __shared__ float norm_l[64];

  const int tid = threadIdx.x;
  const int bh = blockIdx.x;

  if (tid < 64) norm_l[tid] = norm[bh*64 + tid] + 0.01f;
  __syncthreads();

  #pragma unroll
  for (int j = 0; j < 2; ++j){
    int e = tid*8 + j*4;
    int ss = e >> 5, d = e & 31;
    float4 v = *(const float4*)&st_raw[(size_t)bh*2048 + e];
    float c = norm_l[ss];
    st_l[ss][d+0] = v.x / c; st_l[ss][d+1] = v.y / c;
    st_l[ss][d+2] = v.z / c; st_l[ss][d+3] = v.w / c;
  }
  // Wqkv is 96x32 = 3072 floats: 12 rounds of 256
  #pragma unroll
  for (int j = 0; j < 12; ++j){
    int idx = j*256 + tid;
    wq_l[idx >> 5][idx & 31] = Wqkv[idx];
  }
  __syncthreads();

  const int sq = tid >> 2, jg = tid & 3;
  float str[32];
  #pragma unroll
  for (int d4 = 0; d4 < 8; ++d4)
    *(float4*)&str[d4*4] = *(const float4*)&st_l[sq][d4*4];

  #pragma unroll
  for (int jj = 0; jj < 24; ++jj){
    int j = jg + 4*jj;
    float a = 0.f;
    #pragma unroll
    for (int d = 0; d < 32; ++d) a = fmaf(str[d], wq_l[j][d], a);
    qkv_l[sq][j] = a;
  }
  __syncthreads();

  float q[32];
  #pragma unroll
  for (int d = 0; d < 32; ++d) q[d] = qkv_l[sq][d];

  const float scale = 0.17677669529663689f;  // 1/sqrt(32)
  float sc[16];
  #pragma unroll
  for (int jj = 0; jj < 16; ++jj){
    int j2 = jg*16 + jj;
    float a = 0.f;
    #pragma unroll
    for (int d = 0; d < 32; ++d) a = fmaf(q[d], qkv_l[j2][32+d], a);
    sc[jj] = a * scale;
  }
  float mx = sc[0];
  #pragma unroll
  for (int jj = 1; jj < 16; ++jj) mx = fmaxf(mx, sc[jj]);
  mx = fmaxf(mx, __shfl_xor(mx, 1));
  mx = fmaxf(mx, __shfl_xor(mx, 2));
  float sum = 0.f;
  #pragma unroll
  for (int jj = 0; jj < 16; ++jj){ sc[jj] = __expf(sc[jj] - mx); sum += sc[jj]; }
  sum += __shfl_xor(sum, 1);
  sum += __shfl_xor(sum, 2);
  const float inv = 1.0f / sum;

  float o[32];
  #pragma unroll
  for (int d = 0; d < 32; ++d) o[d] = 0.f;
  #pragma unroll
  for (int jj = 0; jj < 16; ++jj){
    int j2 = jg*16 + jj;
    float pv = sc[jj];
    #pragma unroll
    for (int d = 0; d < 32; ++d) o[d] = fmaf(pv, qkv_l[j2][64+d], o[d]);
  }
  #pragma unroll
  for (int d = 0; d < 32; ++d){
    o[d] += __shfl_xor(o[d], 1);
    o[d] += __shfl_xor(o[d], 2);
  }
  float4 r0, r1;
  r0.x = o[jg*8+0]*inv; r0.y = o[jg*8+1]*inv; r0.z = o[jg*8+2]*inv; r0.w = o[jg*8+3]*inv;
  r1.x = o[jg*8+4]*inv; r1.y = o[jg*8+5]*inv; r1.z = o[jg*8+6]*inv; r1.w = o[jg*8+7]*inv;
  *(float4*)&out_sl[(size_t)bh*2048 + sq*32 + jg*8]     = r0;
  *(float4*)&out_sl[(size_t)bh*2048 + sq*32 + jg*8 + 4] = r1;
}

// ---------------------------------------------------------------------------
// K4: deslice out_x[n,h,d] = sum_s w[n,h,s]*out_slice[b,h,s,d] -> bf16 ox
// grid = BN/64, block = 256. os_t stride 70: (12*dd)%32 spreads 8 bank-groups.
// ---------------------------------------------------------------------------
__global__ __launch_bounds__(256)
void k4_deslice(const ushort_t* __restrict__ w_bf,
                const float* __restrict__ out_sl, ushort_t* __restrict__ ox_bf)
{
  __shared__ float w_l[64*68];
  __shared__ float os_t[32*70];

  const int tid = threadIdx.x;
  const int n0 = blockIdx.x * 64;
  const int b = n0 >> 15;
  const int tq = tid >> 4, dd = tid & 15;

  for (int h = 0; h < 8; ++h){
    __syncthreads();
    #pragma unroll
    for (int j = 0; j < 4; ++j){
      int idx2 = j*256 + tid;               // uint2 (4 bf16) index
      int tok = idx2 >> 4, sq4 = (idx2 & 15) << 2;
      uint2 u = *(const uint2*)&w_bf[(size_t)(n0+tok)*512 + h*64 + sq4];
      w_l[tok*68 + sq4+0] = bf2f((ushort_t)(u.x & 0xffff));
      w_l[tok*68 + sq4+1] = bf2f((ushort_t)(u.x >> 16));
      w_l[tok*68 + sq4+2] = bf2f((ushort_t)(u.y & 0xffff));
      w_l[tok*68 + sq4+3] = bf2f((ushort_t)(u.y >> 16));
    }
    #pragma unroll
    for (int j = 0; j < 2; ++j){
      int idx = j*256 + tid;                // float4 index
      int ss = idx >> 3, d4 = (idx & 7) << 2;
      float4 v = *(const float4*)&out_sl[(size_t)(b*8+h)*2048 + ss*32 + d4];
      os_t[(d4+0)*70 + ss] = v.x;
      os_t[(d4+1)*70 + ss] = v.y;
      os_t[(d4+2)*70 + ss] = v.z;
      os_t[(d4+3)*70 + ss] = v.w;
    }
    __syncthreads();

    float a0[4] = {0,0,0,0}, a1[4] = {0,0,0,0};
    #pragma unroll
    for (int s4 = 0; s4 < 16; ++s4){
      const float4 osa = *(const float4*)&os_t[(2*dd)*70   + s4*4];
      const float4 osb = *(const float4*)&os_t[(2*dd+1)*70 + s4*4];
      #pragma unroll
      for (int tt = 0; tt < 4; ++tt){
        const float4 wv = *(const float4*)&w_l[(tq*4+tt)*68 + s4*4];
        a0[tt] = dot4(wv, osa, a0[tt]);
        a1[tt] = dot4(wv, osb, a1[tt]);
      }
    }
    #pragma unroll
    for (int tt = 0; tt < 4; ++tt){
      const size_t n = (size_t)(n0 + tq*4 + tt);
      ox_bf[n*256 + h*32 + 2*dd + 0] = f2bf(a0[tt]);
      ox_bf[n*256 + h*32 + 2*dd + 1] = f2bf(a1[tt]);
    }
  }
}

// ---------------------------------------------------------------------------
// K5: out = ox @ Wout.T + bout. grid = BN/32, block = 256.
// LDS: ox[32][256] 32KB + Wout tile [256][20] 20KB = 52KB -> 3 blocks/CU.
// ---------------------------------------------------------------------------
__global__ __launch_bounds__(256, 3)
void k5_out(const ushort_t* __restrict__ ox_bf, const float* __restrict__ Wout,
            const float* __restrict__ bout, float* __restrict__ out)
{
  __shared__ float smem[8192 + 256*WSTRIDE];   // 52KB
  float* ox_l = smem;                          // [32][256]
  float* wo_t = smem + 8192;                   // [256][WSTRIDE]

  const int tid = threadIdx.x;
  const int n0 = blockIdx.x * 32;

  #pragma unroll
  for (int j = 0; j < 8; ++j){
    int idx4 = j*256 + tid;                  // uint2 (4 bf16) index
    int tok = idx4 >> 6, k4 = (idx4 & 63) << 2;
    uint2 u = *(const uint2*)&ox_bf[(size_t)(n0+tok)*256 + k4];
    ox_l[tok*256 + k4+0] = bf2f((ushort_t)(u.x & 0xffff));
    ox_l[tok*256 + k4+1] = bf2f((ushort_t)(u.x >> 16));
    ox_l[tok*256 + k4+2] = bf2f((ushort_t)(u.y & 0xffff));
    ox_l[tok*256 + k4+3] = bf2f((ushort_t)(u.y >> 16));
  }

  const int ttg = tid >> 6, iq = tid & 63;
  float acc[8][4];
  #pragma unroll
  for (int tt = 0; tt < 8; ++tt)
    #pragma unroll
    for (int m = 0; m < 4; ++m) acc[tt][m] = 0.f;

  for (int c = 0; c < 16; ++c){
    __syncthreads();
    #pragma unroll
    for (int j = 0; j < 4; ++j){
      int idx = j*256 + tid;
      int row = idx >> 2, kk = (idx & 3) << 2;
      *(float4*)&wo_t[row*WSTRIDE + kk] = *(const float4*)&Wout[row*256 + c*16 + kk];
    }
    __syncthreads();
    #pragma unroll
    for (int k4 = 0; k4 < 4; ++k4){
      const int kb = c*16 + k4*4;
      float4 xa[8];
      #pragma unroll
      for (int tt = 0; tt < 8; ++tt)
        xa[tt] = *(const float4*)&ox_l[(ttg*8+tt)*256 + kb];   // broadcast
      #pragma unroll
      for (int m = 0; m < 4; ++m){
        const float4 wv = *(const float4*)&wo_t[(iq + 64*m)*WSTRIDE + k4*4];
        #pragma unroll
        for (int tt = 0; tt < 8; ++tt)
          acc[tt][m] = dot4(xa[tt], wv, acc[tt][m]);
      }
    }
  }

  float br[4];
  #pragma unroll
  for (int m = 0; m < 4; ++m) br[m] = bout[iq + 64*m];
  #pragma unroll
  for (int tt = 0; tt < 8; ++tt){
    const size_t n = (size_t)(n0 + ttg*8 + tt);
    #pragma unroll
    for (int m = 0; m < 4; ++m)
      out[n*256 + iq + 64*m] = acc[tt][m] + br[m];
  }
}

// ---------------------------------------------------------------------------
extern "C" void kernel_launch(void* const* d_in, const int* in_sizes, int n_in,
                              void* d_out, int out_size, void* d_ws, size_t ws_size,
                              hipStream_t stream)
{
  const float* x    = (const float*)d_in[0];
  const float* Wx   = (const float*)d_in[1];
  const float* bx   = (const float*)d_in[2];
  const float* Wf   = (const float*)d_in[3];
  const float* bff  = (const float*)d_in[4];
  const float* Ws   = (const float*)d_in[5];
  const float* bs   = (const float*)d_in[6];
  const float* Wqkv = (const float*)d_in[7];
  const float* Wout = (const float*)d_in[8];
  const float* bout = (const float*)d_in[9];
  const float* temp = (const float*)d_in[10];
  float* out = (float*)d_out;

  char* ws = (char*)d_ws;
  // Workspace layout (96.3 MB total):
  ushort_t* fm_bf = (ushort_t*)ws;                       // 32 MB [BN][256]
  ushort_t* w_bf  = (ushort_t*)(ws + 33554432);          // 64 MB [BN][H][S]
  ushort_t* ox_bf = fm_bf;                               // aliases fm (dead after K2)
  float* norm     = (float*)(ws + 100663296);            // 4 KB  [B][H][S]
  float* st_raw   = (float*)(ws + 100667392);            // 128KB [B][H][S][DH]
  float* out_sl   = (float*)(ws + 100798464);            // 128KB [B][H][S][DH]

  // zero the atomically-accumulated buffers (norm + st_raw are contiguous)
  hipMemsetAsync(ws + 100663296, 0, 4096 + 131072, stream);

  k1_proj<<<BN_/32, 256, 0, stream>>>(x, Wx, bx, Wf, bff, Ws, bs, temp, fm_bf, w_bf);
  k2_slicetok<<<dim3(64, H_, B_), 256, 0, stream>>>(w_bf, fm_bf, st_raw, norm);
  k3_attn<<<B_*H_, 256, 0, stream>>>(st_raw, norm, Wqkv, out_sl);
  k4_deslice<<<BN_/64, 256, 0, stream>>>(w_bf, out_sl, ox_bf);
  k5_out<<<BN_/32, 256, 0, stream>>>(ox_bf, Wout, bout, out);

  (void)in_sizes; (void)n_in; (void)out_size; (void)ws_size;
}

// Round 7
// 479.533 us; speedup vs baseline: 1.5945x; 1.5945x over previous
//
#include <hip/hip_runtime.h>
#include <hip/hip_bf16.h>

#define B_     2
#define N_     32768
#define DIM_   256
#define H_     8
#define DH_    32
#define S_     64
#define INNER_ 256
#define BN_    (B_*N_)

typedef unsigned short ushort_t;
typedef unsigned int   uint_t;
typedef __attribute__((ext_vector_type(8))) short bf16x8;   // 8 bf16 = 4 VGPR
typedef __attribute__((ext_vector_type(4))) float f32x4;

static __device__ __forceinline__ float bf2f(ushort_t u){
  union { uint_t i; float f; } c; c.i = ((uint_t)u) << 16; return c.f;
}
static __device__ __forceinline__ ushort_t f2bf(float f){
  union { float f; uint_t i; } c; c.f = f;
  uint_t x = c.i;
  uint_t r = x + 0x7fffu + ((x >> 16) & 1u);   // RNE
  return (ushort_t)(r >> 16);
}
// split fp32 into hi+lo bf16 (hi = RNE(v), lo = RNE(v - hi)); v-hi is exact in fp32
static __device__ __forceinline__ void split2(float v, ushort_t& h, ushort_t& l){
  h = f2bf(v);
  l = f2bf(v - bf2f(h));
}
static __device__ __forceinline__ float dot4(float4 a, float4 b, float acc){
  acc = fmaf(a.x, b.x, acc); acc = fmaf(a.y, b.y, acc);
  acc = fmaf(a.z, b.z, acc); acc = fmaf(a.w, b.w, acc);
  return acc;
}

// ---------------------------------------------------------------------------
// K0: pre-split weights into hi/lo bf16.  Wc = [Wx; Wf] stacked [512][256].
// grid = 192, block = 256 (49152 float4s total).
// ---------------------------------------------------------------------------
__global__ __launch_bounds__(256)
void k0_convw(const float* __restrict__ Wx, const float* __restrict__ Wf,
              const float* __restrict__ Wout,
              ushort_t* __restrict__ Wc_hi, ushort_t* __restrict__ Wc_lo,
              ushort_t* __restrict__ Wo_hi, ushort_t* __restrict__ Wo_lo)
{
  int idx = blockIdx.x*256 + threadIdx.x;     // float4 index
  float4 v; ushort_t* dh; ushort_t* dl; int e4;
  if (idx < 32768){
    const float* src; int i4;
    if (idx < 16384){ src = Wx; i4 = idx; } else { src = Wf; i4 = idx - 16384; }
    v = ((const float4*)src)[i4];
    dh = Wc_hi; dl = Wc_lo; e4 = idx;
  } else {
    int i4 = idx - 32768;
    v = ((const float4*)Wout)[i4];
    dh = Wo_hi; dl = Wo_lo; e4 = i4;
  }
  ushort_t h0,h1,h2,h3,l0,l1,l2,l3;
  split2(v.x,h0,l0); split2(v.y,h1,l1); split2(v.z,h2,l2); split2(v.w,h3,l3);
  uint2 ph, pl;
  ph.x = (uint_t)h0 | ((uint_t)h1<<16); ph.y = (uint_t)h2 | ((uint_t)h3<<16);
  pl.x = (uint_t)l0 | ((uint_t)l1<<16); pl.y = (uint_t)l2 | ((uint_t)l3<<16);
  *(uint2*)&dh[e4*4] = ph;
  *(uint2*)&dl[e4*4] = pl;
}

// ---------------------------------------------------------------------------
// K1a: xm = x@Wx.T + bx via 3-term split-bf16 MFMA, fused slice_proj+softmax.
// grid = BN/32, block = 256 (4 waves, each owns a 64-col quadrant of N=256).
// Wave tile 32x64: M_rep=2, N_rep=4, acc 2x4 f32x4.
// LDS: Ah/Al[32][40] + Bh/Bl[256][40] bf16 (stride 40 = conflict-free b128),
// 46080B; xm_l[32][260] fp32 aliases after GEMM.
// ---------------------------------------------------------------------------
__global__ __launch_bounds__(256)
void k1a_xm(const float* __restrict__ x,
            const ushort_t* __restrict__ Wc_hi, const ushort_t* __restrict__ Wc_lo,
            const float* __restrict__ bx,
            const float* __restrict__ Ws, const float* __restrict__ bs,
            const float* __restrict__ temp,
            ushort_t* __restrict__ w_bf)
{
  __shared__ __align__(16) ushort_t smu[23040];   // 46080 B
  ushort_t* Ah = smu;                 // [32][40]
  ushort_t* Al = smu + 1280;
  ushort_t* Bh = smu + 2560;          // [256][40]
  ushort_t* Bl = smu + 12800;
  float* xm_l = (float*)smu;          // [32][260] fp32, aliases staging

  const int tid  = threadIdx.x;
  const int m0   = blockIdx.x * 32;
  const int lane = tid & 63;
  const int wn   = tid >> 6;          // wave = col quadrant
  const int l15  = lane & 15, l16 = lane >> 4;
  const int asr  = tid >> 3, asp = tid & 7;   // A staging: row, float4-pos

  f32x4 acc[2][4];
  #pragma unroll
  for (int i=0;i<2;++i)
    #pragma unroll
    for (int j=0;j<4;++j) acc[i][j] = (f32x4){0.f,0.f,0.f,0.f};

  for (int ks = 0; ks < 8; ++ks){
    const int k0 = ks*32;
    __syncthreads();
    // stage A (x tile 32x32 fp32 -> hi/lo bf16)
    {
      float4 v = *(const float4*)&x[(size_t)(m0+asr)*256 + k0 + asp*4];
      ushort_t h0,h1,h2,h3,l0,l1,l2,l3;
      split2(v.x,h0,l0); split2(v.y,h1,l1); split2(v.z,h2,l2); split2(v.w,h3,l3);
      uint2 ph, pl;
      ph.x = (uint_t)h0 | ((uint_t)h1<<16); ph.y = (uint_t)h2 | ((uint_t)h3<<16);
      pl.x = (uint_t)l0 | ((uint_t)l1<<16); pl.y = (uint_t)l2 | ((uint_t)l3<<16);
      *(uint2*)&Ah[asr*40 + asp*4] = ph;
      *(uint2*)&Al[asr*40 + asp*4] = pl;
    }
    // stage B (Wx rows 0..255, pre-split) — 4 x 16B chunks each for hi and lo
    #pragma unroll
    for (int i=0;i<4;++i){
      int c = i*256 + tid;
      int r = c >> 2, o = c & 3;
      *(uint4*)&Bh[r*40 + o*8] = *(const uint4*)&Wc_hi[(size_t)r*256 + k0 + o*8];
      *(uint4*)&Bl[r*40 + o*8] = *(const uint4*)&Wc_lo[(size_t)r*256 + k0 + o*8];
    }
    __syncthreads();
    bf16x8 ah[2], alo[2], bh[4], blo[4];
    #pragma unroll
    for (int mt=0;mt<2;++mt){
      ah[mt]  = *(const bf16x8*)&Ah[(mt*16+l15)*40 + l16*8];
      alo[mt] = *(const bf16x8*)&Al[(mt*16+l15)*40 + l16*8];
    }
    #pragma unroll
    for (int nt=0;nt<4;++nt){
      bh[nt]  = *(const bf16x8*)&Bh[(wn*64+nt*16+l15)*40 + l16*8];
      blo[nt] = *(const bf16x8*)&Bl[(wn*64+nt*16+l15)*40 + l16*8];
    }
    #pragma unroll
    for (int mt=0;mt<2;++mt)
      #pragma unroll
      for (int nt=0;nt<4;++nt){
        acc[mt][nt] = __builtin_amdgcn_mfma_f32_16x16x32_bf16(ah[mt],  bh[nt],  acc[mt][nt],0,0,0);
        acc[mt][nt] = __builtin_amdgcn_mfma_f32_16x16x32_bf16(alo[mt], bh[nt],  acc[mt][nt],0,0,0);
        acc[mt][nt] = __builtin_amdgcn_mfma_f32_16x16x32_bf16(ah[mt],  blo[nt], acc[mt][nt],0,0,0);
      }
  }
  __syncthreads();
  // epilogue: xm (+bias) into LDS fp32.  C/D map: row=(lane>>4)*4+r, col=lane&15
  {
    float bxr[4];
    #pragma unroll
    for (int nt=0;nt<4;++nt) bxr[nt] = bx[wn*64 + nt*16 + l15];
    #pragma unroll
    for (int mt=0;mt<2;++mt)
      #pragma unroll
      for (int nt=0;nt<4;++nt)
        #pragma unroll
        for (int r=0;r<4;++r)
          xm_l[(mt*16 + l16*4 + r)*260 + wn*64 + nt*16 + l15] = acc[mt][nt][r] + bxr[nt];
  }
  __syncthreads();

  // phase 2: slice_proj + temp-softmax; thread = (token t2, head hh)
  const int t2 = tid >> 3, hh = tid & 7;
  const size_t n = (size_t)(m0 + t2);
  float xmr[32];
  #pragma unroll
  for (int d4 = 0; d4 < 8; ++d4)
    *(float4*)&xmr[d4*4] = *(const float4*)&xm_l[t2*260 + hh*32 + d4*4];

  float tmpr = temp[hh];
  tmpr = fminf(fmaxf(tmpr, 0.5f), 5.0f);

  float sp[64];
  #pragma unroll
  for (int s = 0; s < 64; ++s){
    float a = bs[s];
    #pragma unroll
    for (int d4 = 0; d4 < 8; ++d4){
      float4 wv = *(const float4*)&Ws[s*32 + d4*4];   // wave-uniform
      a = fmaf(xmr[d4*4+0], wv.x, a);
      a = fmaf(xmr[d4*4+1], wv.y, a);
      a = fmaf(xmr[d4*4+2], wv.z, a);
      a = fmaf(xmr[d4*4+3], wv.w, a);
    }
    sp[s] = a / tmpr;
  }
  float mx = sp[0];
  #pragma unroll
  for (int s = 1; s < 64; ++s) mx = fmaxf(mx, sp[s]);
  float sum = 0.f;
  #pragma unroll
  for (int s = 0; s < 64; ++s){ sp[s] = __expf(sp[s] - mx); sum += sp[s]; }
  const float inv = 1.0f / sum;

  uint4* dst = (uint4*)&w_bf[n*512 + hh*64];
  #pragma unroll
  for (int j = 0; j < 8; ++j){
    uint4 pk;
    pk.x = (uint_t)f2bf(sp[8*j+0]*inv) | ((uint_t)f2bf(sp[8*j+1]*inv) << 16);
    pk.y = (uint_t)f2bf(sp[8*j+2]*inv) | ((uint_t)f2bf(sp[8*j+3]*inv) << 16);
    pk.z = (uint_t)f2bf(sp[8*j+4]*inv) | ((uint_t)f2bf(sp[8*j+5]*inv) << 16);
    pk.w = (uint_t)f2bf(sp[8*j+6]*inv) | ((uint_t)f2bf(sp[8*j+7]*inv) << 16);
    dst[j] = pk;
  }
}

// ---------------------------------------------------------------------------
// K1c: fm = x@Wf.T + bf via 3-term split-bf16 MFMA -> bf16.
// grid = (BN/128, 2), block = 256.  Block tile 128x128, waves 2x2 (64x64 ea).
// LDS: Ah/Al/Bh/Bl [128][40] = 40960B.
// ---------------------------------------------------------------------------
__global__ __launch_bounds__(256)
void k1c_fm(const float* __restrict__ x,
            const ushort_t* __restrict__ Wc_hi, const ushort_t* __restrict__ Wc_lo,
            const float* __restrict__ bfb,
            ushort_t* __restrict__ fm_bf)
{
  __shared__ __align__(16) ushort_t smu[20480];   // 40960 B
  ushort_t* Ah = smu;
  ushort_t* Al = smu + 5120;
  ushort_t* Bh = smu + 10240;
  ushort_t* Bl = smu + 15360;

  const int tid  = threadIdx.x;
  const int m0   = blockIdx.x * 128;
  const int j    = blockIdx.y;              // fm col block (0/1)
  const int wrow = 256 + j*128;             // Wc row base (Wf half)
  const int lane = tid & 63, w = tid >> 6;
  const int wm = w >> 1, wn2 = w & 1;
  const int l15 = lane & 15, l16 = lane >> 4;

  f32x4 acc[4][4];
  #pragma unroll
  for (int i=0;i<4;++i)
    #pragma unroll
    for (int jj=0;jj<4;++jj) acc[i][jj] = (f32x4){0.f,0.f,0.f,0.f};

  for (int ks = 0; ks < 8; ++ks){
    const int k0 = ks*32;
    __syncthreads();
    // stage A: 128x32 fp32 -> hi/lo (4 float4 per thread)
    #pragma unroll
    for (int i=0;i<4;++i){
      int c = i*256 + tid;
      int r = c >> 3, p = c & 7;
      float4 v = *(const float4*)&x[(size_t)(m0+r)*256 + k0 + p*4];
      ushort_t h0,h1,h2,h3,l0,l1,l2,l3;
      split2(v.x,h0,l0); split2(v.y,h1,l1); split2(v.z,h2,l2); split2(v.w,h3,l3);
      uint2 ph, pl;
      ph.x = (uint_t)h0 | ((uint_t)h1<<16); ph.y = (uint_t)h2 | ((uint_t)h3<<16);
      pl.x = (uint_t)l0 | ((uint_t)l1<<16); pl.y = (uint_t)l2 | ((uint_t)l3<<16);
      *(uint2*)&Ah[r*40 + p*4] = ph;
      *(uint2*)&Al[r*40 + p*4] = pl;
    }
    // stage B: Wf rows (pre-split), 2 x 16B chunks per thread per matrix
    #pragma unroll
    for (int i=0;i<2;++i){
      int c = i*256 + tid;
      int r = c >> 2, o = c & 3;
      *(uint4*)&Bh[r*40 + o*8] = *(const uint4*)&Wc_hi[(size_t)(wrow+r)*256 + k0 + o*8];
      *(uint4*)&Bl[r*40 + o*8] = *(const uint4*)&Wc_lo[(size_t)(wrow+r)*256 + k0 + o*8];
    }
    __syncthreads();
    bf16x8 ah[4], alo[4], bh[4], blo[4];
    #pragma unroll
    for (int mt=0;mt<4;++mt){
      ah[mt]  = *(const bf16x8*)&Ah[(wm*64 + mt*16 + l15)*40 + l16*8];
      alo[mt] = *(const bf16x8*)&Al[(wm*64 + mt*16 + l15)*40 + l16*8];
    }
    #pragma unroll
    for (int nt=0;nt<4;++nt){
      bh[nt]  = *(const bf16x8*)&Bh[(wn2*64 + nt*16 + l15)*40 + l16*8];
      blo[nt] = *(const bf16x8*)&Bl[(wn2*64 + nt*16 + l15)*40 + l16*8];
    }
    #pragma unroll
    for (int mt=0;mt<4;++mt)
      #pragma unroll
      for (int nt=0;nt<4;++nt){
        acc[mt][nt] = __builtin_amdgcn_mfma_f32_16x16x32_bf16(ah[mt],  bh[nt],  acc[mt][nt],0,0,0);
        acc[mt][nt] = __builtin_amdgcn_mfma_f32_16x16x32_bf16(alo[mt], bh[nt],  acc[mt][nt],0,0,0);
        acc[mt][nt] = __builtin_amdgcn_mfma_f32_16x16x32_bf16(ah[mt],  blo[nt], acc[mt][nt],0,0,0);
      }
  }
  // epilogue -> fm bf16
  float bfr[4];
  #pragma unroll
  for (int nt=0;nt<4;++nt) bfr[nt] = bfb[j*128 + wn2*64 + nt*16 + l15];
  #pragma unroll
  for (int mt=0;mt<4;++mt)
    #pragma unroll
    for (int nt=0;nt<4;++nt)
      #pragma unroll
      for (int r=0;r<4;++r){
        int row = m0 + wm*64 + mt*16 + l16*4 + r;
        int col = j*128 + wn2*64 + nt*16 + l15;
        fm_bf[(size_t)row*256 + col] = f2bf(acc[mt][nt][r] + bfr[nt]);
      }
}

// ---------------------------------------------------------------------------
// K2: slice_token_raw[b,h,s,d] = sum_n w*fm ; slice_norm[b,h,s] = sum_n w
// grid = (64 chunks, H, B), block = 256.  (unchanged)
// ---------------------------------------------------------------------------
__global__ __launch_bounds__(256)
void k2_slicetok(const ushort_t* __restrict__ w_bf,
                 const ushort_t* __restrict__ fm_bf,
                 float* __restrict__ st_raw, float* __restrict__ norm)
{
  __shared__ float wg[8][64];
  __shared__ float fg[8][32];
  __shared__ float nred[8][64];

  const int tid = threadIdx.x;
  const int b = blockIdx.z, h = blockIdx.y, chunk = blockIdx.x;
  const int n0 = b*N_ + chunk*512;
  const int s = tid >> 2, dq = tid & 3;
  const int lg = tid >> 5, ls2 = tid & 31;

  float acc[8];
  #pragma unroll
  for (int k = 0; k < 8; ++k) acc[k] = 0.f;
  float nacc0 = 0.f, nacc1 = 0.f;

  for (int it = 0; it < 64; ++it){
    const int nb = n0 + it*8;
    __syncthreads();
    {
      uint_t wu = *(const uint_t*)&w_bf[(size_t)(nb+lg)*512 + h*64 + ls2*2];
      float w0 = bf2f((ushort_t)(wu & 0xffff));
      float w1 = bf2f((ushort_t)(wu >> 16));
      wg[lg][ls2*2]   = w0;
      wg[lg][ls2*2+1] = w1;
      nacc0 += w0; nacc1 += w1;
      fg[lg][ls2] = bf2f(fm_bf[(size_t)(nb+lg)*256 + h*32 + ls2]);
    }
    __syncthreads();
    #pragma unroll
    for (int g = 0; g < 8; ++g){
      const float wv = wg[g][s];
      #pragma unroll
      for (int k = 0; k < 8; ++k)
        acc[k] = fmaf(wv, fg[g][dq*8 + k], acc[k]);
    }
  }
  #pragma unroll
  for (int k = 0; k < 8; ++k)
    atomicAdd(&st_raw[((size_t)(b*8 + h)*64 + s)*32 + dq*8 + k], acc[k]);

  __syncthreads();
  nred[lg][2*ls2]   = nacc0;
  nred[lg][2*ls2+1] = nacc1;
  __syncthreads();
  if (tid < 64){
    float t = 0.f;
    #pragma unroll
    for (int g = 0; g < 8; ++g) t += nred[g][tid];
    atomicAdd(&norm[(b*8 + h)*64 + tid], t);
  }
}

// ---------------------------------------------------------------------------
// K3: tiny SDPA over slices per (b,h). grid = 16, block = 256.  (unchanged)
// ---------------------------------------------------------------------------
__global__ __launch_bounds__(256)
void k3_attn(const float* __restrict__ st_raw, const float* __restrict__ norm,
             const float* __restrict__ Wqkv, float* __restrict__ out_sl)
{
  __shared__ float st_l[64][36];
  __shared__ float wq_l[96][36];
  __shared__ float qkv_l[64][100];
  __shared__ float norm_l[64];

  const int tid = threadIdx.x;
  const int bh = blockIdx.x;

  if (tid < 64) norm_l[tid] = norm[bh*64 + tid] + 0.01f;
  __syncthreads();

  #pragma unroll
  for (int j = 0; j < 2; ++j){
    int e = tid*8 + j*4;
    int ss = e >> 5, d = e & 31;
    float4 v = *(const float4*)&st_raw[(size_t)bh*2048 + e];
    float c = norm_l[ss];
    st_l[ss][d+0] = v.x / c; st_l[ss][d+1] = v.y / c;
    st_l[ss][d+2] = v.z / c; st_l[ss][d+3] = v.w / c;
  }
  // Wqkv is 96x32 = 3072 floats: 12 rounds of 256
  #pragma unroll
  for (int j = 0; j < 12; ++j){
    int idx = j*256 + tid;
    wq_l[idx >> 5][idx & 31] = Wqkv[idx];
  }
  __syncthreads();

  const int sq = tid >> 2, jg = tid & 3;
  float str[32];
  #pragma unroll
  for (int d4 = 0; d4 < 8; ++d4)
    *(float4*)&str[d4*4] = *(const float4*)&st_l[sq][d4*4];

  #pragma unroll
  for (int jj = 0; jj < 24; ++jj){
    int j = jg + 4*jj;
    float a = 0.f;
    #pragma unroll
    for (int d = 0; d < 32; ++d) a = fmaf(str[d], wq_l[j][d], a);
    qkv_l[sq][j] = a;
  }
  __syncthreads();

  float q[32];
  #pragma unroll
  for (int d = 0; d < 32; ++d) q[d] = qkv_l[sq][d];

  const float scale = 0.17677669529663689f;  // 1/sqrt(32)
  float sc[16];
  #pragma unroll
  for (int jj = 0; jj < 16; ++jj){
    int j2 = jg*16 + jj;
    float a = 0.f;
    #pragma unroll
    for (int d = 0; d < 32; ++d) a = fmaf(q[d], qkv_l[j2][32+d], a);
    sc[jj] = a * scale;
  }
  float mx = sc[0];
  #pragma unroll
  for (int jj = 1; jj < 16; ++jj) mx = fmaxf(mx, sc[jj]);
  mx = fmaxf(mx, __shfl_xor(mx, 1));
  mx = fmaxf(mx, __shfl_xor(mx, 2));
  float sum = 0.f;
  #pragma unroll
  for (int jj = 0; jj < 16; ++jj){ sc[jj] = __expf(sc[jj] - mx); sum += sc[jj]; }
  sum += __shfl_xor(sum, 1);
  sum += __shfl_xor(sum, 2);
  const float inv = 1.0f / sum;

  float o[32];
  #pragma unroll
  for (int d = 0; d < 32; ++d) o[d] = 0.f;
  #pragma unroll
  for (int jj = 0; jj < 16; ++jj){
    int j2 = jg*16 + jj;
    float pv = sc[jj];
    #pragma unroll
    for (int d = 0; d < 32; ++d) o[d] = fmaf(pv, qkv_l[j2][64+d], o[d]);
  }
  #pragma unroll
  for (int d = 0; d < 32; ++d){
    o[d] += __shfl_xor(o[d], 1);
    o[d] += __shfl_xor(o[d], 2);
  }
  float4 r0, r1;
  r0.x = o[jg*8+0]*inv; r0.y = o[jg*8+1]*inv; r0.z = o[jg*8+2]*inv; r0.w = o[jg*8+3]*inv;
  r1.x = o[jg*8+4]*inv; r1.y = o[jg*8+5]*inv; r1.z = o[jg*8+6]*inv; r1.w = o[jg*8+7]*inv;
  *(float4*)&out_sl[(size_t)bh*2048 + sq*32 + jg*8]     = r0;
  *(float4*)&out_sl[(size_t)bh*2048 + sq*32 + jg*8 + 4] = r1;
}

// ---------------------------------------------------------------------------
// K4: deslice out_x[n,h,d] = sum_s w[n,h,s]*out_slice[b,h,s,d] -> bf16 ox
// grid = BN/64, block = 256.  (unchanged)
// ---------------------------------------------------------------------------
__global__ __launch_bounds__(256)
void k4_deslice(const ushort_t* __restrict__ w_bf,
                const float* __restrict__ out_sl, ushort_t* __restrict__ ox_bf)
{
  __shared__ float w_l[64*68];
  __shared__ float os_t[32*70];

  const int tid = threadIdx.x;
  const int n0 = blockIdx.x * 64;
  const int b = n0 >> 15;
  const int tq = tid >> 4, dd = tid & 15;

  for (int h = 0; h < 8; ++h){
    __syncthreads();
    #pragma unroll
    for (int j = 0; j < 4; ++j){
      int idx2 = j*256 + tid;               // uint2 (4 bf16) index
      int tok = idx2 >> 4, sq4 = (idx2 & 15) << 2;
      uint2 u = *(const uint2*)&w_bf[(size_t)(n0+tok)*512 + h*64 + sq4];
      w_l[tok*68 + sq4+0] = bf2f((ushort_t)(u.x & 0xffff));
      w_l[tok*68 + sq4+1] = bf2f((ushort_t)(u.x >> 16));
      w_l[tok*68 + sq4+2] = bf2f((ushort_t)(u.y & 0xffff));
      w_l[tok*68 + sq4+3] = bf2f((ushort_t)(u.y >> 16));
    }
    #pragma unroll
    for (int j = 0; j < 2; ++j){
      int idx = j*256 + tid;                // float4 index
      int ss = idx >> 3, d4 = (idx & 7) << 2;
      float4 v = *(const float4*)&out_sl[(size_t)(b*8+h)*2048 + ss*32 + d4];
      os_t[(d4+0)*70 + ss] = v.x;
      os_t[(d4+1)*70 + ss] = v.y;
      os_t[(d4+2)*70 + ss] = v.z;
      os_t[(d4+3)*70 + ss] = v.w;
    }
    __syncthreads();

    float a0[4] = {0,0,0,0}, a1[4] = {0,0,0,0};
    #pragma unroll
    for (int s4 = 0; s4 < 16; ++s4){
      const float4 osa = *(const float4*)&os_t[(2*dd)*70   + s4*4];
      const float4 osb = *(const float4*)&os_t[(2*dd+1)*70 + s4*4];
      #pragma unroll
      for (int tt = 0; tt < 4; ++tt){
        const float4 wv = *(const float4*)&w_l[(tq*4+tt)*68 + s4*4];
        a0[tt] = dot4(wv, osa, a0[tt]);
        a1[tt] = dot4(wv, osb, a1[tt]);
      }
    }
    #pragma unroll
    for (int tt = 0; tt < 4; ++tt){
      const size_t n = (size_t)(n0 + tq*4 + tt);
      ox_bf[n*256 + h*32 + 2*dd + 0] = f2bf(a0[tt]);
      ox_bf[n*256 + h*32 + 2*dd + 1] = f2bf(a1[tt]);
    }
  }
}

// ---------------------------------------------------------------------------
// K5: out = ox @ Wout.T + bout via 2-term MFMA (A already exact bf16).
// grid = (BN/128, 2), block = 256.  LDS: A[128][40] + Bh/Bl[128][40] = 30720B.
// ---------------------------------------------------------------------------
__global__ __launch_bounds__(256)
void k5_mfma(const ushort_t* __restrict__ ox_bf,
             const ushort_t* __restrict__ Wo_hi, const ushort_t* __restrict__ Wo_lo,
             const float* __restrict__ bout, float* __restrict__ out)
{
  __shared__ __align__(16) ushort_t smu[15360];   // 30720 B
  ushort_t* Aa = smu;
  ushort_t* Bh = smu + 5120;
  ushort_t* Bl = smu + 10240;

  const int tid  = threadIdx.x;
  const int m0   = blockIdx.x * 128;
  const int j    = blockIdx.y;
  const int lane = tid & 63, w = tid >> 6;
  const int wm = w >> 1, wn2 = w & 1;
  const int l15 = lane & 15, l16 = lane >> 4;

  f32x4 acc[4][4];
  #pragma unroll
  for (int i=0;i<4;++i)
    #pragma unroll
    for (int jj=0;jj<4;++jj) acc[i][jj] = (f32x4){0.f,0.f,0.f,0.f};

  for (int ks = 0; ks < 8; ++ks){
    const int k0 = ks*32;
    __syncthreads();
    #pragma unroll
    for (int i=0;i<2;++i){
      int c = i*256 + tid;
      int r = c >> 2, o = c & 3;
      *(uint4*)&Aa[r*40 + o*8] = *(const uint4*)&ox_bf[(size_t)(m0+r)*256 + k0 + o*8];
      *(uint4*)&Bh[r*40 + o*8] = *(const uint4*)&Wo_hi[(size_t)(j*128+r)*256 + k0 + o*8];
      *(uint4*)&Bl[r*40 + o*8] = *(const uint4*)&Wo_lo[(size_t)(j*128+r)*256 + k0 + o*8];
    }
    __syncthreads();
    bf16x8 av[4], bh[4], blo[4];
    #pragma unroll
    for (int mt=0;mt<4;++mt)
      av[mt] = *(const bf16x8*)&Aa[(wm*64 + mt*16 + l15)*40 + l16*8];
    #pragma unroll
    for (int nt=0;nt<4;++nt){
      bh[nt]  = *(const bf16x8*)&Bh[(wn2*64 + nt*16 + l15)*40 + l16*8];
      blo[nt] = *(const bf16x8*)&Bl[(wn2*64 + nt*16 + l15)*40 + l16*8];
    }
    #pragma unroll
    for (int mt=0;mt<4;++mt)
      #pragma unroll
      for (int nt=0;nt<4;++nt){
        acc[mt][nt] = __builtin_amdgcn_mfma_f32_16x16x32_bf16(av[mt], bh[nt],  acc[mt][nt],0,0,0);
        acc[mt][nt] = __builtin_amdgcn_mfma_f32_16x16x32_bf16(av[mt], blo[nt], acc[mt][nt],0,0,0);
      }
  }
  float br[4];
  #pragma unroll
  for (int nt=0;nt<4;++nt) br[nt] = bout[j*128 + wn2*64 + nt*16 + l15];
  #pragma unroll
  for (int mt=0;mt<4;++mt)
    #pragma unroll
    for (int nt=0;nt<4;++nt)
      #pragma unroll
      for (int r=0;r<4;++r){
        int row = m0 + wm*64 + mt*16 + l16*4 + r;
        int col = j*128 + wn2*64 + nt*16 + l15;
        out[(size_t)row*256 + col] = acc[mt][nt][r] + br[nt];
      }
}

// ---------------------------------------------------------------------------
extern "C" void kernel_launch(void* const* d_in, const int* in_sizes, int n_in,
                              void* d_out, int out_size, void* d_ws, size_t ws_size,
                              hipStream_t stream)
{
  const float* x    = (const float*)d_in[0];
  const float* Wx   = (const float*)d_in[1];
  const float* bx   = (const float*)d_in[2];
  const float* Wf   = (const float*)d_in[3];
  const float* bff  = (const float*)d_in[4];
  const float* Ws   = (const float*)d_in[5];
  const float* bs   = (const float*)d_in[6];
  const float* Wqkv = (const float*)d_in[7];
  const float* Wout = (const float*)d_in[8];
  const float* bout = (const float*)d_in[9];
  const float* temp = (const float*)d_in[10];
  float* out = (float*)d_out;

  char* ws = (char*)d_ws;
  // Workspace layout (~101.7 MB):
  ushort_t* fm_bf = (ushort_t*)ws;                       // 32 MB [BN][256]
  ushort_t* w_bf  = (ushort_t*)(ws + 33554432);          // 64 MB [BN][H][S]
  ushort_t* ox_bf = fm_bf;                               // aliases fm (dead after K2)
  float* norm     = (float*)(ws + 100663296);            // 4 KB  [B][H][S]
  float* st_raw   = (float*)(ws + 100667392);            // 128KB [B][H][S][DH]
  float* out_sl   = (float*)(ws + 100798464);            // 128KB [B][H][S][DH]
  ushort_t* Wc_hi = (ushort_t*)(ws + 100929536);         // 256KB [512][256] bf16
  ushort_t* Wc_lo = (ushort_t*)(ws + 101191680);         // 256KB
  ushort_t* Wo_hi = (ushort_t*)(ws + 101453824);         // 128KB [256][256] bf16
  ushort_t* Wo_lo = (ushort_t*)(ws + 101584896);         // 128KB -> end 101715968

  // zero the atomically-accumulated buffers (norm + st_raw are contiguous)
  hipMemsetAsync(ws + 100663296, 0, 4096 + 131072, stream);

  k0_convw<<<192, 256, 0, stream>>>(Wx, Wf, Wout, Wc_hi, Wc_lo, Wo_hi, Wo_lo);
  k1a_xm<<<BN_/32, 256, 0, stream>>>(x, Wc_hi, Wc_lo, bx, Ws, bs, temp, w_bf);
  k1c_fm<<<dim3(BN_/128, 2), 256, 0, stream>>>(x, Wc_hi, Wc_lo, bff, fm_bf);
  k2_slicetok<<<dim3(64, H_, B_), 256, 0, stream>>>(w_bf, fm_bf, st_raw, norm);
  k3_attn<<<B_*H_, 256, 0, stream>>>(st_raw, norm, Wqkv, out_sl);
  k4_deslice<<<BN_/64, 256, 0, stream>>>(w_bf, out_sl, ox_bf);
  k5_mfma<<<dim3(BN_/128, 2), 256, 0, stream>>>(ox_bf, Wo_hi, Wo_lo, bout, out);

  (void)in_sizes; (void)n_in; (void)out_size; (void)ws_size;
}

// Round 9
// 456.055 us; speedup vs baseline: 1.6766x; 1.0515x over previous
//
#include <hip/hip_runtime.h>
#include <hip/hip_bf16.h>

#define B_     2
#define N_     32768
#define DIM_   256
#define H_     8
#define DH_    32
#define S_     64
#define INNER_ 256
#define BN_    (B_*N_)

typedef unsigned short ushort_t;
typedef unsigned int   uint_t;
typedef __attribute__((ext_vector_type(8))) short bf16x8;   // 8 bf16 = 4 VGPR
typedef __attribute__((ext_vector_type(4))) float f32x4;

static __device__ __forceinline__ float bf2f(ushort_t u){
  union { uint_t i; float f; } c; c.i = ((uint_t)u) << 16; return c.f;
}
static __device__ __forceinline__ ushort_t f2bf(float f){
  union { float f; uint_t i; } c; c.f = f;
  uint_t x = c.i;
  uint_t r = x + 0x7fffu + ((x >> 16) & 1u);   // RNE
  return (ushort_t)(r >> 16);
}
// split fp32 into hi+lo bf16 (hi = RNE(v), lo = RNE(v - hi)); v-hi is exact in fp32
static __device__ __forceinline__ void split2(float v, ushort_t& h, ushort_t& l){
  h = f2bf(v);
  l = f2bf(v - bf2f(h));
}
static __device__ __forceinline__ float dot4(float4 a, float4 b, float acc){
  acc = fmaf(a.x, b.x, acc); acc = fmaf(a.y, b.y, acc);
  acc = fmaf(a.z, b.z, acc); acc = fmaf(a.w, b.w, acc);
  return acc;
}

// ---------------------------------------------------------------------------
// K0: pre-split weights into hi/lo bf16.  Wc = [Wx; Wf] stacked [512][256].
// grid = 192, block = 256 (49152 float4s total).
// ---------------------------------------------------------------------------
__global__ __launch_bounds__(256)
void k0_convw(const float* __restrict__ Wx, const float* __restrict__ Wf,
              const float* __restrict__ Wout,
              ushort_t* __restrict__ Wc_hi, ushort_t* __restrict__ Wc_lo,
              ushort_t* __restrict__ Wo_hi, ushort_t* __restrict__ Wo_lo)
{
  int idx = blockIdx.x*256 + threadIdx.x;     // float4 index
  float4 v; ushort_t* dh; ushort_t* dl; int e4;
  if (idx < 32768){
    const float* src; int i4;
    if (idx < 16384){ src = Wx; i4 = idx; } else { src = Wf; i4 = idx - 16384; }
    v = ((const float4*)src)[i4];
    dh = Wc_hi; dl = Wc_lo; e4 = idx;
  } else {
    int i4 = idx - 32768;
    v = ((const float4*)Wout)[i4];
    dh = Wo_hi; dl = Wo_lo; e4 = i4;
  }
  ushort_t h0,h1,h2,h3,l0,l1,l2,l3;
  split2(v.x,h0,l0); split2(v.y,h1,l1); split2(v.z,h2,l2); split2(v.w,h3,l3);
  uint2 ph, pl;
  ph.x = (uint_t)h0 | ((uint_t)h1<<16); ph.y = (uint_t)h2 | ((uint_t)h3<<16);
  pl.x = (uint_t)l0 | ((uint_t)l1<<16); pl.y = (uint_t)l2 | ((uint_t)l3<<16);
  *(uint2*)&dh[e4*4] = ph;
  *(uint2*)&dl[e4*4] = pl;
}

// ---------------------------------------------------------------------------
// K1x: xm = x@Wx.T + bx (3-term split-bf16 MFMA) fused with slice_proj+softmax.
// grid = (BN/64, 2), block = 256.
// Block tile 64 tokens x 128 cols (= heads 4j..4j+3 -- slice_proj for head h
// needs only that head's 32 dims, so softmax is block-local).
// Waves 2x2, wave tile 32x64: acc 2x4 f32x4.
// LDS: Ah/Al[64][40] + Bh/Bl[128][40] staging (30720B) aliased by
// xm_l[64][132] fp32 (33792B) -> 33.8KB -> 4 blocks/CU (vs k1a's 2).
// xm_l layout row*132 + (col>>5)*33 + (col&31): phase-2 read bank =
// (tid+d)%32 -> conflict-free (k1a had 8-way, 8.1M conflict cycles).
// ---------------------------------------------------------------------------
__global__ __launch_bounds__(256)
void k1x_xm(const float* __restrict__ x,
            const ushort_t* __restrict__ Wc_hi, const ushort_t* __restrict__ Wc_lo,
            const float* __restrict__ bx,
            const float* __restrict__ Ws, const float* __restrict__ bs,
            const float* __restrict__ temp,
            ushort_t* __restrict__ w_bf)
{
  __shared__ __align__(16) ushort_t smu[16896];   // 33792 B
  ushort_t* Ah = smu;                  // [64][40]
  ushort_t* Al = smu + 2560;
  ushort_t* Bh = smu + 5120;           // [128][40]
  ushort_t* Bl = smu + 10240;          // staging ends at 30720 B
  float* xm_l = (float*)smu;           // [64][132] fp32, aliases staging

  const int tid  = threadIdx.x;
  const int m0   = blockIdx.x * 64;
  const int j    = blockIdx.y;         // col block: heads 4j..4j+3
  const int lane = tid & 63, w = tid >> 6;
  const int wm = w >> 1, wn2 = w & 1;
  const int l15 = lane & 15, l16 = lane >> 4;

  f32x4 acc[2][4];
  #pragma unroll
  for (int i=0;i<2;++i)
    #pragma unroll
    for (int q=0;q<4;++q) acc[i][q] = (f32x4){0.f,0.f,0.f,0.f};

  for (int ks = 0; ks < 8; ++ks){
    const int k0 = ks*32;
    __syncthreads();
    // stage A: 64x32 fp32 -> hi/lo (2 float4 per thread)
    #pragma unroll
    for (int i=0;i<2;++i){
      int c = i*256 + tid;
      int r = c >> 3, p = c & 7;
      float4 v = *(const float4*)&x[(size_t)(m0+r)*256 + k0 + p*4];
      ushort_t h0,h1,h2,h3,l0,l1,l2,l3;
      split2(v.x,h0,l0); split2(v.y,h1,l1); split2(v.z,h2,l2); split2(v.w,h3,l3);
      uint2 ph, pl;
      ph.x = (uint_t)h0 | ((uint_t)h1<<16); ph.y = (uint_t)h2 | ((uint_t)h3<<16);
      pl.x = (uint_t)l0 | ((uint_t)l1<<16); pl.y = (uint_t)l2 | ((uint_t)l3<<16);
      *(uint2*)&Ah[r*40 + p*4] = ph;
      *(uint2*)&Al[r*40 + p*4] = pl;
    }
    // stage B: Wx rows j*128..j*128+127 (pre-split), 2 uint4/thread/matrix
    #pragma unroll
    for (int i=0;i<2;++i){
      int c = i*256 + tid;
      int r = c >> 2, o = c & 3;
      *(uint4*)&Bh[r*40 + o*8] = *(const uint4*)&Wc_hi[(size_t)(j*128+r)*256 + k0 + o*8];
      *(uint4*)&Bl[r*40 + o*8] = *(const uint4*)&Wc_lo[(size_t)(j*128+r)*256 + k0 + o*8];
    }
    __syncthreads();
    bf16x8 ah[2], alo[2], bh[4], blo[4];
    #pragma unroll
    for (int mt=0;mt<2;++mt){
      ah[mt]  = *(const bf16x8*)&Ah[(wm*32 + mt*16 + l15)*40 + l16*8];
      alo[mt] = *(const bf16x8*)&Al[(wm*32 + mt*16 + l15)*40 + l16*8];
    }
    #pragma unroll
    for (int nt=0;nt<4;++nt){
      bh[nt]  = *(const bf16x8*)&Bh[(wn2*64 + nt*16 + l15)*40 + l16*8];
      blo[nt] = *(const bf16x8*)&Bl[(wn2*64 + nt*16 + l15)*40 + l16*8];
    }
    #pragma unroll
    for (int mt=0;mt<2;++mt)
      #pragma unroll
      for (int nt=0;nt<4;++nt){
        acc[mt][nt] = __builtin_amdgcn_mfma_f32_16x16x32_bf16(ah[mt],  bh[nt],  acc[mt][nt],0,0,0);
        acc[mt][nt] = __builtin_amdgcn_mfma_f32_16x16x32_bf16(alo[mt], bh[nt],  acc[mt][nt],0,0,0);
        acc[mt][nt] = __builtin_amdgcn_mfma_f32_16x16x32_bf16(ah[mt],  blo[nt], acc[mt][nt],0,0,0);
      }
  }
  __syncthreads();   // staging reads done; safe to overwrite with xm_l

  // epilogue: xm (+bias) -> xm_l, head-padded layout.
  // C/D map: row=(lane>>4)*4+r, col=lane&15
  {
    float bxr[4];
    #pragma unroll
    for (int nt=0;nt<4;++nt) bxr[nt] = bx[j*128 + wn2*64 + nt*16 + l15];
    #pragma unroll
    for (int mt=0;mt<2;++mt)
      #pragma unroll
      for (int nt=0;nt<4;++nt){
        const int coll = wn2*64 + nt*16 + l15;
        const int cb = (coll >> 5)*33 + (coll & 31);
        #pragma unroll
        for (int r=0;r<4;++r){
          const int row = wm*32 + mt*16 + l16*4 + r;
          xm_l[row*132 + cb] = acc[mt][nt][r] + bxr[nt];
        }
      }
  }
  __syncthreads();

  // phase 2: slice_proj + temp-softmax; thread = (token t2, local head hl)
  const int t2 = tid >> 2, hl = tid & 3;
  const int hh = j*4 + hl;
  const size_t n = (size_t)(m0 + t2);
  float xmr[32];
  const int xbase = t2*132 + hl*33;
  #pragma unroll
  for (int d = 0; d < 32; ++d)
    xmr[d] = xm_l[xbase + d];            // bank = (tid+d)%32: conflict-free

  float tmpr = temp[hh];
  tmpr = fminf(fmaxf(tmpr, 0.5f), 5.0f);

  float sp[64];
  #pragma unroll
  for (int s = 0; s < 64; ++s){
    float a = bs[s];
    #pragma unroll
    for (int d4 = 0; d4 < 8; ++d4){
      float4 wv = *(const float4*)&Ws[s*32 + d4*4];   // wave-uniform
      a = fmaf(xmr[d4*4+0], wv.x, a);
      a = fmaf(xmr[d4*4+1], wv.y, a);
      a = fmaf(xmr[d4*4+2], wv.z, a);
      a = fmaf(xmr[d4*4+3], wv.w, a);
    }
    sp[s] = a / tmpr;
  }
  float mx = sp[0];
  #pragma unroll
  for (int s = 1; s < 64; ++s) mx = fmaxf(mx, sp[s]);
  float sum = 0.f;
  #pragma unroll
  for (int s = 0; s < 64; ++s){ sp[s] = __expf(sp[s] - mx); sum += sp[s]; }
  const float inv = 1.0f / sum;

  uint4* dst = (uint4*)&w_bf[n*512 + hh*64];
  #pragma unroll
  for (int q = 0; q < 8; ++q){
    uint4 pk;
    pk.x = (uint_t)f2bf(sp[8*q+0]*inv) | ((uint_t)f2bf(sp[8*q+1]*inv) << 16);
    pk.y = (uint_t)f2bf(sp[8*q+2]*inv) | ((uint_t)f2bf(sp[8*q+3]*inv) << 16);
    pk.z = (uint_t)f2bf(sp[8*q+4]*inv) | ((uint_t)f2bf(sp[8*q+5]*inv) << 16);
    pk.w = (uint_t)f2bf(sp[8*q+6]*inv) | ((uint_t)f2bf(sp[8*q+7]*inv) << 16);
    dst[q] = pk;
  }
}

// ---------------------------------------------------------------------------
// K1c: fm = x@Wf.T + bf via 3-term split-bf16 MFMA -> bf16.  (unchanged)
// grid = (BN/128, 2), block = 256.  Block tile 128x128, waves 2x2 (64x64 ea).
// LDS: Ah/Al/Bh/Bl [128][40] = 40960B.
// ---------------------------------------------------------------------------
__global__ __launch_bounds__(256)
void k1c_fm(const float* __restrict__ x,
            const ushort_t* __restrict__ Wc_hi, const ushort_t* __restrict__ Wc_lo,
            const float* __restrict__ bfb,
            ushort_t* __restrict__ fm_bf)
{
  __shared__ __align__(16) ushort_t smu[20480];   // 40960 B
  ushort_t* Ah = smu;
  ushort_t* Al = smu + 5120;
  ushort_t* Bh = smu + 10240;
  ushort_t* Bl = smu + 15360;

  const int tid  = threadIdx.x;
  const int m0   = blockIdx.x * 128;
  const int j    = blockIdx.y;              // fm col block (0/1)
  const int wrow = 256 + j*128;             // Wc row base (Wf half)
  const int lane = tid & 63, w = tid >> 6;
  const int wm = w >> 1, wn2 = w & 1;
  const int l15 = lane & 15, l16 = lane >> 4;

  f32x4 acc[4][4];
  #pragma unroll
  for (int i=0;i<4;++i)
    #pragma unroll
    for (int jj=0;jj<4;++jj) acc[i][jj] = (f32x4){0.f,0.f,0.f,0.f};

  for (int ks = 0; ks < 8; ++ks){
    const int k0 = ks*32;
    __syncthreads();
    // stage A: 128x32 fp32 -> hi/lo (4 float4 per thread)
    #pragma unroll
    for (int i=0;i<4;++i){
      int c = i*256 + tid;
      int r = c >> 3, p = c & 7;
      float4 v = *(const float4*)&x[(size_t)(m0+r)*256 + k0 + p*4];
      ushort_t h0,h1,h2,h3,l0,l1,l2,l3;
      split2(v.x,h0,l0); split2(v.y,h1,l1); split2(v.z,h2,l2); split2(v.w,h3,l3);
      uint2 ph, pl;
      ph.x = (uint_t)h0 | ((uint_t)h1<<16); ph.y = (uint_t)h2 | ((uint_t)h3<<16);
      pl.x = (uint_t)l0 | ((uint_t)l1<<16); pl.y = (uint_t)l2 | ((uint_t)l3<<16);
      *(uint2*)&Ah[r*40 + p*4] = ph;
      *(uint2*)&Al[r*40 + p*4] = pl;
    }
    // stage B: Wf rows (pre-split), 2 x 16B chunks per thread per matrix
    #pragma unroll
    for (int i=0;i<2;++i){
      int c = i*256 + tid;
      int r = c >> 2, o = c & 3;
      *(uint4*)&Bh[r*40 + o*8] = *(const uint4*)&Wc_hi[(size_t)(wrow+r)*256 + k0 + o*8];
      *(uint4*)&Bl[r*40 + o*8] = *(const uint4*)&Wc_lo[(size_t)(wrow+r)*256 + k0 + o*8];
    }
    __syncthreads();
    bf16x8 ah[4], alo[4], bh[4], blo[4];
    #pragma unroll
    for (int mt=0;mt<4;++mt){
      ah[mt]  = *(const bf16x8*)&Ah[(wm*64 + mt*16 + l15)*40 + l16*8];
      alo[mt] = *(const bf16x8*)&Al[(wm*64 + mt*16 + l15)*40 + l16*8];
    }
    #pragma unroll
    for (int nt=0;nt<4;++nt){
      bh[nt]  = *(const bf16x8*)&Bh[(wn2*64 + nt*16 + l15)*40 + l16*8];
      blo[nt] = *(const bf16x8*)&Bl[(wn2*64 + nt*16 + l15)*40 + l16*8];
    }
    #pragma unroll
    for (int mt=0;mt<4;++mt)
      #pragma unroll
      for (int nt=0;nt<4;++nt){
        acc[mt][nt] = __builtin_amdgcn_mfma_f32_16x16x32_bf16(ah[mt],  bh[nt],  acc[mt][nt],0,0,0);
        acc[mt][nt] = __builtin_amdgcn_mfma_f32_16x16x32_bf16(alo[mt], bh[nt],  acc[mt][nt],0,0,0);
        acc[mt][nt] = __builtin_amdgcn_mfma_f32_16x16x32_bf16(ah[mt],  blo[nt], acc[mt][nt],0,0,0);
      }
  }
  // epilogue -> fm bf16
  float bfr[4];
  #pragma unroll
  for (int nt=0;nt<4;++nt) bfr[nt] = bfb[j*128 + wn2*64 + nt*16 + l15];
  #pragma unroll
  for (int mt=0;mt<4;++mt)
    #pragma unroll
    for (int nt=0;nt<4;++nt)
      #pragma unroll
      for (int r=0;r<4;++r){
        int row = m0 + wm*64 + mt*16 + l16*4 + r;
        int col = j*128 + wn2*64 + nt*16 + l15;
        fm_bf[(size_t)row*256 + col] = f2bf(acc[mt][nt][r] + bfr[nt]);
      }
}

// ---------------------------------------------------------------------------
// K2: slice_token_raw[b,h,s,d] = sum_n w*fm ; slice_norm[b,h,s] = sum_n w
// grid = (64 chunks, H, B), block = 256.  (unchanged)
// ---------------------------------------------------------------------------
__global__ __launch_bounds__(256)
void k2_slicetok(const ushort_t* __restrict__ w_bf,
                 const ushort_t* __restrict__ fm_bf,
                 float* __restrict__ st_raw, float* __restrict__ norm)
{
  __shared__ float wg[8][64];
  __shared__ float fg[8][32];
  __shared__ float nred[8][64];

  const int tid = threadIdx.x;
  const int b = blockIdx.z, h = blockIdx.y, chunk = blockIdx.x;
  const int n0 = b*N_ + chunk*512;
  const int s = tid >> 2, dq = tid & 3;
  const int lg = tid >> 5, ls2 = tid & 31;

  float acc[8];
  #pragma unroll
  for (int k = 0; k < 8; ++k) acc[k] = 0.f;
  float nacc0 = 0.f, nacc1 = 0.f;

  for (int it = 0; it < 64; ++it){
    const int nb = n0 + it*8;
    __syncthreads();
    {
      uint_t wu = *(const uint_t*)&w_bf[(size_t)(nb+lg)*512 + h*64 + ls2*2];
      float w0 = bf2f((ushort_t)(wu & 0xffff));
      float w1 = bf2f((ushort_t)(wu >> 16));
      wg[lg][ls2*2]   = w0;
      wg[lg][ls2*2+1] = w1;
      nacc0 += w0; nacc1 += w1;
      fg[lg][ls2] = bf2f(fm_bf[(size_t)(nb+lg)*256 + h*32 + ls2]);
    }
    __syncthreads();
    #pragma unroll
    for (int g = 0; g < 8; ++g){
      const float wv = wg[g][s];
      #pragma unroll
      for (int k = 0; k < 8; ++k)
        acc[k] = fmaf(wv, fg[g][dq*8 + k], acc[k]);
    }
  }
  #pragma unroll
  for (int k = 0; k < 8; ++k)
    atomicAdd(&st_raw[((size_t)(b*8 + h)*64 + s)*32 + dq*8 + k], acc[k]);

  __syncthreads();
  nred[lg][2*ls2]   = nacc0;
  nred[lg][2*ls2+1] = nacc1;
  __syncthreads();
  if (tid < 64){
    float t = 0.f;
    #pragma unroll
    for (int g = 0; g < 8; ++g) t += nred[g][tid];
    atomicAdd(&norm[(b*8 + h)*64 + tid], t);
  }
}

// ---------------------------------------------------------------------------
// K3: tiny SDPA over slices per (b,h). grid = 16, block = 256.  (unchanged)
// ---------------------------------------------------------------------------
__global__ __launch_bounds__(256)
void k3_attn(const float* __restrict__ st_raw, const float* __restrict__ norm,
             const float* __restrict__ Wqkv, float* __restrict__ out_sl)
{
  __shared__ float st_l[64][36];
  __shared__ float wq_l[96][36];
  __shared__ float qkv_l[64][100];
  __shared__ float norm_l[64];

  const int tid = threadIdx.x;
  const int bh = blockIdx.x;

  if (tid < 64) norm_l[tid] = norm[bh*64 + tid] + 0.01f;
  __syncthreads();

  #pragma unroll
  for (int j = 0; j < 2; ++j){
    int e = tid*8 + j*4;
    int ss = e >> 5, d = e & 31;
    float4 v = *(const float4*)&st_raw[(size_t)bh*2048 + e];
    float c = norm_l[ss];
    st_l[ss][d+0] = v.x / c; st_l[ss][d+1] = v.y / c;
    st_l[ss][d+2] = v.z / c; st_l[ss][d+3] = v.w / c;
  }
  // Wqkv is 96x32 = 3072 floats: 12 rounds of 256
  #pragma unroll
  for (int j = 0; j < 12; ++j){
    int idx = j*256 + tid;
    wq_l[idx >> 5][idx & 31] = Wqkv[idx];
  }
  __syncthreads();

  const int sq = tid >> 2, jg = tid & 3;
  float str[32];
  #pragma unroll
  for (int d4 = 0; d4 < 8; ++d4)
    *(float4*)&str[d4*4] = *(const float4*)&st_l[sq][d4*4];

  #pragma unroll
  for (int jj = 0; jj < 24; ++jj){
    int j = jg + 4*jj;
    float a = 0.f;
    #pragma unroll
    for (int d = 0; d < 32; ++d) a = fmaf(str[d], wq_l[j][d], a);
    qkv_l[sq][j] = a;
  }
  __syncthreads();

  float q[32];
  #pragma unroll
  for (int d = 0; d < 32; ++d) q[d] = qkv_l[sq][d];

  const float scale = 0.17677669529663689f;  // 1/sqrt(32)
  float sc[16];
  #pragma unroll
  for (int jj = 0; jj < 16; ++jj){
    int j2 = jg*16 + jj;
    float a = 0.f;
    #pragma unroll
    for (int d = 0; d < 32; ++d) a = fmaf(q[d], qkv_l[j2][32+d], a);
    sc[jj] = a * scale;
  }
  float mx = sc[0];
  #pragma unroll
  for (int jj = 1; jj < 16; ++jj) mx = fmaxf(mx, sc[jj]);
  mx = fmaxf(mx, __shfl_xor(mx, 1));
  mx = fmaxf(mx, __shfl_xor(mx, 2));
  float sum = 0.f;
  #pragma unroll
  for (int jj = 0; jj < 16; ++jj){ sc[jj] = __expf(sc[jj] - mx); sum += sc[jj]; }
  sum += __shfl_xor(sum, 1);
  sum += __shfl_xor(sum, 2);
  const float inv = 1.0f / sum;

  float o[32];
  #pragma unroll
  for (int d = 0; d < 32; ++d) o[d] = 0.f;
  #pragma unroll
  for (int jj = 0; jj < 16; ++jj){
    int j2 = jg*16 + jj;
    float pv = sc[jj];
    #pragma unroll
    for (int d = 0; d < 32; ++d) o[d] = fmaf(pv, qkv_l[j2][64+d], o[d]);
  }
  #pragma unroll
  for (int d = 0; d < 32; ++d){
    o[d] += __shfl_xor(o[d], 1);
    o[d] += __shfl_xor(o[d], 2);
  }
  float4 r0, r1;
  r0.x = o[jg*8+0]*inv; r0.y = o[jg*8+1]*inv; r0.z = o[jg*8+2]*inv; r0.w = o[jg*8+3]*inv;
  r1.x = o[jg*8+4]*inv; r1.y = o[jg*8+5]*inv; r1.z = o[jg*8+6]*inv; r1.w = o[jg*8+7]*inv;
  *(float4*)&out_sl[(size_t)bh*2048 + sq*32 + jg*8]     = r0;
  *(float4*)&out_sl[(size_t)bh*2048 + sq*32 + jg*8 + 4] = r1;
}

// ---------------------------------------------------------------------------
// K4: deslice out_x[n,h,d] = sum_s w[n,h,s]*out_slice[b,h,s,d] -> bf16 ox
// grid = BN/64, block = 256.  (unchanged)
// ---------------------------------------------------------------------------
__global__ __launch_bounds__(256)
void k4_deslice(const ushort_t* __restrict__ w_bf,
                const float* __restrict__ out_sl, ushort_t* __restrict__ ox_bf)
{
  __shared__ float w_l[64*68];
  __shared__ float os_t[32*70];

  const int tid = threadIdx.x;
  const int n0 = blockIdx.x * 64;
  const int b = n0 >> 15;
  const int tq = tid >> 4, dd = tid & 15;

  for (int h = 0; h < 8; ++h){
    __syncthreads();
    #pragma unroll
    for (int j = 0; j < 4; ++j){
      int idx2 = j*256 + tid;               // uint2 (4 bf16) index
      int tok = idx2 >> 4, sq4 = (idx2 & 15) << 2;
      uint2 u = *(const uint2*)&w_bf[(size_t)(n0+tok)*512 + h*64 + sq4];
      w_l[tok*68 + sq4+0] = bf2f((ushort_t)(u.x & 0xffff));
      w_l[tok*68 + sq4+1] = bf2f((ushort_t)(u.x >> 16));
      w_l[tok*68 + sq4+2] = bf2f((ushort_t)(u.y & 0xffff));
      w_l[tok*68 + sq4+3] = bf2f((ushort_t)(u.y >> 16));
    }
    #pragma unroll
    for (int j = 0; j < 2; ++j){
      int idx = j*256 + tid;                // float4 index
      int ss = idx >> 3, d4 = (idx & 7) << 2;
      float4 v = *(const float4*)&out_sl[(size_t)(b*8+h)*2048 + ss*32 + d4];
      os_t[(d4+0)*70 + ss] = v.x;
      os_t[(d4+1)*70 + ss] = v.y;
      os_t[(d4+2)*70 + ss] = v.z;
      os_t[(d4+3)*70 + ss] = v.w;
    }
    __syncthreads();

    float a0[4] = {0,0,0,0}, a1[4] = {0,0,0,0};
    #pragma unroll
    for (int s4 = 0; s4 < 16; ++s4){
      const float4 osa = *(const float4*)&os_t[(2*dd)*70   + s4*4];
      const float4 osb = *(const float4*)&os_t[(2*dd+1)*70 + s4*4];
      #pragma unroll
      for (int tt = 0; tt < 4; ++tt){
        const float4 wv = *(const float4*)&w_l[(tq*4+tt)*68 + s4*4];
        a0[tt] = dot4(wv, osa, a0[tt]);
        a1[tt] = dot4(wv, osb, a1[tt]);
      }
    }
    #pragma unroll
    for (int tt = 0; tt < 4; ++tt){
      const size_t n = (size_t)(n0 + tq*4 + tt);
      ox_bf[n*256 + h*32 + 2*dd + 0] = f2bf(a0[tt]);
      ox_bf[n*256 + h*32 + 2*dd + 1] = f2bf(a1[tt]);
    }
  }
}

// ---------------------------------------------------------------------------
// K5: out = ox @ Wout.T + bout via 2-term MFMA (A already exact bf16).
// grid = (BN/128, 2), block = 256.  (unchanged)
// ---------------------------------------------------------------------------
__global__ __launch_bounds__(256)
void k5_mfma(const ushort_t* __restrict__ ox_bf,
             const ushort_t* __restrict__ Wo_hi, const ushort_t* __restrict__ Wo_lo,
             const float* __restrict__ bout, float* __restrict__ out)
{
  __shared__ __align__(16) ushort_t smu[15360];   // 30720 B
  ushort_t* Aa = smu;
  ushort_t* Bh = smu + 5120;
  ushort_t* Bl = smu + 10240;

  const int tid  = threadIdx.x;
  const int m0   = blockIdx.x * 128;
  const int j    = blockIdx.y;
  const int lane = tid & 63, w = tid >> 6;
  const int wm = w >> 1, wn2 = w & 1;
  const int l15 = lane & 15, l16 = lane >> 4;

  f32x4 acc[4][4];
  #pragma unroll
  for (int i=0;i<4;++i)
    #pragma unroll
    for (int jj=0;jj<4;++jj) acc[i][jj] = (f32x4){0.f,0.f,0.f,0.f};

  for (int ks = 0; ks < 8; ++ks){
    const int k0 = ks*32;
    __syncthreads();
    #pragma unroll
    for (int i=0;i<2;++i){
      int c = i*256 + tid;
      int r = c >> 2, o = c & 3;
      *(uint4*)&Aa[r*40 + o*8] = *(const uint4*)&ox_bf[(size_t)(m0+r)*256 + k0 + o*8];
      *(uint4*)&Bh[r*40 + o*8] = *(const uint4*)&Wo_hi[(size_t)(j*128+r)*256 + k0 + o*8];
      *(uint4*)&Bl[r*40 + o*8] = *(const uint4*)&Wo_lo[(size_t)(j*128+r)*256 + k0 + o*8];
    }
    __syncthreads();
    bf16x8 av[4], bh[4], blo[4];
    #pragma unroll
    for (int mt=0;mt<4;++mt)
      av[mt] = *(const bf16x8*)&Aa[(wm*64 + mt*16 + l15)*40 + l16*8];
    #pragma unroll
    for (int nt=0;nt<4;++nt){
      bh[nt]  = *(const bf16x8*)&Bh[(wn2*64 + nt*16 + l15)*40 + l16*8];
      blo[nt] = *(const bf16x8*)&Bl[(wn2*64 + nt*16 + l15)*40 + l16*8];
    }
    #pragma unroll
    for (int mt=0;mt<4;++mt)
      #pragma unroll
      for (int nt=0;nt<4;++nt){
        acc[mt][nt] = __builtin_amdgcn_mfma_f32_16x16x32_bf16(av[mt], bh[nt],  acc[mt][nt],0,0,0);
        acc[mt][nt] = __builtin_amdgcn_mfma_f32_16x16x32_bf16(av[mt], blo[nt], acc[mt][nt],0,0,0);
      }
  }
  float br[4];
  #pragma unroll
  for (int nt=0;nt<4;++nt) br[nt] = bout[j*128 + wn2*64 + nt*16 + l15];
  #pragma unroll
  for (int mt=0;mt<4;++mt)
    #pragma unroll
    for (int nt=0;nt<4;++nt)
      #pragma unroll
      for (int r=0;r<4;++r){
        int row = m0 + wm*64 + mt*16 + l16*4 + r;
        int col = j*128 + wn2*64 + nt*16 + l15;
        out[(size_t)row*256 + col] = acc[mt][nt][r] + br[nt];
      }
}

// ---------------------------------------------------------------------------
extern "C" void kernel_launch(void* const* d_in, const int* in_sizes, int n_in,
                              void* d_out, int out_size, void* d_ws, size_t ws_size,
                              hipStream_t stream)
{
  const float* x    = (const float*)d_in[0];
  const float* Wx   = (const float*)d_in[1];
  const float* bx   = (const float*)d_in[2];
  const float* Wf   = (const float*)d_in[3];
  const float* bff  = (const float*)d_in[4];
  const float* Ws   = (const float*)d_in[5];
  const float* bs   = (const float*)d_in[6];
  const float* Wqkv = (const float*)d_in[7];
  const float* Wout = (const float*)d_in[8];
  const float* bout = (const float*)d_in[9];
  const float* temp = (const float*)d_in[10];
  float* out = (float*)d_out;

  char* ws = (char*)d_ws;
  // Workspace layout (~101.7 MB):
  ushort_t* fm_bf = (ushort_t*)ws;                       // 32 MB [BN][256]
  ushort_t* w_bf  = (ushort_t*)(ws + 33554432);          // 64 MB [BN][H][S]
  ushort_t* ox_bf = fm_bf;                               // aliases fm (dead after K2)
  float* norm     = (float*)(ws + 100663296);            // 4 KB  [B][H][S]
  float* st_raw   = (float*)(ws + 100667392);            // 128KB [B][H][S][DH]
  float* out_sl   = (float*)(ws + 100798464);            // 128KB [B][H][S][DH]
  ushort_t* Wc_hi = (ushort_t*)(ws + 100929536);         // 256KB [512][256] bf16
  ushort_t* Wc_lo = (ushort_t*)(ws + 101191680);         // 256KB
  ushort_t* Wo_hi = (ushort_t*)(ws + 101453824);         // 128KB [256][256] bf16
  ushort_t* Wo_lo = (ushort_t*)(ws + 101584896);         // 128KB -> end 101715968

  // zero the atomically-accumulated buffers (norm + st_raw are contiguous)
  hipMemsetAsync(ws + 100663296, 0, 4096 + 131072, stream);

  k0_convw<<<192, 256, 0, stream>>>(Wx, Wf, Wout, Wc_hi, Wc_lo, Wo_hi, Wo_lo);
  k1x_xm<<<dim3(BN_/64, 2), 256, 0, stream>>>(x, Wc_hi, Wc_lo, bx, Ws, bs, temp, w_bf);
  k1c_fm<<<dim3(BN_/128, 2), 256, 0, stream>>>(x, Wc_hi, Wc_lo, bff, fm_bf);
  k2_slicetok<<<dim3(64, H_, B_), 256, 0, stream>>>(w_bf, fm_bf, st_raw, norm);
  k3_attn<<<B_*H_, 256, 0, stream>>>(st_raw, norm, Wqkv, out_sl);
  k4_deslice<<<BN_/64, 256, 0, stream>>>(w_bf, out_sl, ox_bf);
  k5_mfma<<<dim3(BN_/128, 2), 256, 0, stream>>>(ox_bf, Wo_hi, Wo_lo, bout, out);

  (void)in_sizes; (void)n_in; (void)out_size; (void)ws_size;
}